// Round 9
// baseline (231.955 us; speedup 1.0000x reference)
//
#include <hip/hip_runtime.h>
#include <hip/hip_bf16.h>

typedef __bf16 bf16x8 __attribute__((ext_vector_type(8)));
typedef short  s16x4  __attribute__((ext_vector_type(4)));
typedef float  f32x4  __attribute__((ext_vector_type(4)));

static constexpr int S  = 64;    // DIM_S
static constexpr int C  = 8;     // DIM_C (experts)
static constexpr int HD = 256;   // hidden width

__device__ __forceinline__ unsigned short f2bf(float f) {
  __hip_bfloat16 b = __float2bfloat16(f);
  unsigned short u;
  __builtin_memcpy(&u, &b, 2);
  return u;
}

// async global->LDS DMA, 16 B per lane; lds dest = wave-uniform base + lane*16
__device__ __forceinline__ void gl2lds16(const void* g, void* l) {
  __builtin_amdgcn_global_load_lds(
      (const __attribute__((address_space(1))) unsigned int*)g,
      (__attribute__((address_space(3))) unsigned int*)l, 16, 0, 0);
}

// LDS-tiled transposes, coalesced both sides.
// blocks 0..511:  W2 [C][256k][256n] -> W2T bf16 [C][256n][256k]
// blocks 512..639: W1 [C][64s][256h] -> W1T bf16 [C][256h][64s]
__global__ __launch_bounds__(256) void prep_weights(
    const float* __restrict__ W1, const float* __restrict__ W2,
    unsigned short* __restrict__ W1T, unsigned short* __restrict__ W2T)
{
  __shared__ float tile[32][33];
  const int tid = threadIdx.x, cl = tid & 31, r0 = tid >> 5;
  const int b = blockIdx.x;
  if (b < 512) {
    const int c = b >> 6, t = b & 63, kt = t >> 3, nt = t & 7;
    const float* src = W2 + c * 65536;
    #pragma unroll
    for (int i = 0; i < 4; ++i) {
      int r = r0 + 8 * i;
      tile[r][cl] = src[(kt * 32 + r) * 256 + nt * 32 + cl];
    }
    __syncthreads();
    unsigned short* dst = W2T + c * 65536;
    #pragma unroll
    for (int i = 0; i < 4; ++i) {
      int r = r0 + 8 * i;
      dst[(nt * 32 + r) * 256 + kt * 32 + cl] = f2bf(tile[cl][r]);
    }
  } else {
    const int bb = b - 512;
    const int c = bb >> 4, t = bb & 15, st2 = t >> 3, ht = t & 7;
    const float* src = W1 + c * 16384;
    #pragma unroll
    for (int i = 0; i < 4; ++i) {
      int r = r0 + 8 * i;
      tile[r][cl] = src[(st2 * 32 + r) * 256 + ht * 32 + cl];
    }
    __syncthreads();
    unsigned short* dst = W1T + c * 16384;
    #pragma unroll
    for (int i = 0; i < 4; ++i) {
      int r = r0 + 8 * i;
      dst[(ht * 32 + r) * 64 + st2 * 32 + cl] = f2bf(tile[cl][r]);
    }
  }
}

// One block: 256 batch rows x 1 expert. 4 waves, 64 rows/wave.
// Phase 1 (16x16x32, transposed h1^T): D-layout (col=batch=l15, row=hidden=q*4+r)
// IS the A-layout of 16x16x16bf16 MFMA -> packed accs feed phase 2 directly,
// no LDS transpose at all. Phase 2: 16x16x16 MFMAs, W2T 64-row chunks via
// global_load_lds ping-pong (sW <-> reused sU), 5 barriers total.
// LDS: sU 32768 + sW 32768 = 65536 B -> 2 blocks/CU (register-capped anyway).
__global__ __launch_bounds__(256, 2) void moe_fused(
    const float* __restrict__ st,
    const unsigned short* __restrict__ W1T,
    const unsigned short* __restrict__ W2T,
    const float* __restrict__ b1,
    const float* __restrict__ b2,
    const float* __restrict__ W3,
    const float* __restrict__ b3,
    float* __restrict__ out)
{
  // sU: phase 1 = st tile bf16 [256 rows][64], granule-swizzled (g^(r&7));
  //     phase 2 = W2 chunk buffer (odd chunks). sW: even chunks. 32 KB each.
  __shared__ __align__(16) unsigned short sU[64 * 256];
  __shared__ __align__(16) unsigned short sW[64 * 256];

  const int tid  = threadIdx.x;
  const int lane = tid & 63;
  const int wv   = tid >> 6;          // wave -> batch rows [wv*64, wv*64+64)
  const int l15  = lane & 15;
  const int q    = lane >> 4;
  const int c    = blockIdx.x >> 8;
  const int row0 = (blockIdx.x & 255) * 256;

  const unsigned short* W1c = W1T + c * HD * S;
  const unsigned short* W2c = W2T + c * HD * HD;
  const float bb3 = b3[c];

  // ---- stage st (fp32 -> bf16) into sU; wave-private rows, swizzled ----
  #pragma unroll
  for (int it = 0; it < 8; ++it) {
    const int r = wv * 64 + it * 8 + (lane >> 3);   // block-local batch row
    const int g = lane & 7;                          // logical 16B granule
    const float4* p = reinterpret_cast<const float4*>(
        st + (size_t)(row0 + r) * S + g * 8);
    float4 x = p[0], y = p[1];
    union { uint4 u4; unsigned short us[8]; } pk;
    pk.us[0] = f2bf(x.x); pk.us[1] = f2bf(x.y); pk.us[2] = f2bf(x.z); pk.us[3] = f2bf(x.w);
    pk.us[4] = f2bf(y.x); pk.us[5] = f2bf(y.y); pk.us[6] = f2bf(y.z); pk.us[7] = f2bf(y.w);
    *reinterpret_cast<uint4*>(sU + r * 64 + ((g ^ (r & 7)) << 3)) = pk.u4;
  }
  __asm__ __volatile__("s_waitcnt lgkmcnt(0)" ::: "memory");

  // ---- phase 1: h1^T = W1^T @ st^T (16x16x32), 4 quarters of 64 hidden ----
  // aF[kk][nt]: phase-2 A-frags for 16x16x16 (m=batch=l15, k=q*4+reg) — built
  // straight from the MFMA D-layout, no LDS round-trip.
  s16x4 aF[16][4];
  #pragma unroll
  for (int cc = 0; cc < 4; ++cc) {
    f32x4 bias[4];
    #pragma unroll
    for (int mt = 0; mt < 4; ++mt)
      bias[mt] = *reinterpret_cast<const f32x4*>(
          b1 + c * HD + cc * 64 + mt * 16 + q * 4);

    f32x4 acc[4][4];   // [mt(hidden)][nt(batch)]
    #pragma unroll
    for (int mt = 0; mt < 4; ++mt)
      #pragma unroll
      for (int nt = 0; nt < 4; ++nt)
        acc[mt][nt] = (f32x4){0.f, 0.f, 0.f, 0.f};

    #pragma unroll
    for (int ks = 0; ks < 2; ++ks) {
      bf16x8 aW[4];
      #pragma unroll
      for (int mt = 0; mt < 4; ++mt)
        aW[mt] = *reinterpret_cast<const bf16x8*>(
            W1c + (cc * 64 + mt * 16 + l15) * S + ks * 32 + q * 8);
      bf16x8 bB[4];
      #pragma unroll
      for (int nt = 0; nt < 4; ++nt) {
        const int r = wv * 64 + nt * 16 + l15;
        const int g = ks * 4 + q;
        bB[nt] = *reinterpret_cast<const bf16x8*>(
            sU + r * 64 + ((g ^ (r & 7)) << 3));
      }
      #pragma unroll
      for (int mt = 0; mt < 4; ++mt)
        #pragma unroll
        for (int nt = 0; nt < 4; ++nt)
          acc[mt][nt] = __builtin_amdgcn_mfma_f32_16x16x32_bf16(
              aW[mt], bB[nt], acc[mt][nt], 0, 0, 0);
    }

    // DMA prologue for W2 chunk 0 -> sW: issued in the LAST quarter, after all
    // its global loads, before the (VALU-only) epilogue. 8 x 1KB per wave.
    if (cc == 3) {
      #pragma unroll
      for (int i = 0; i < 8; ++i) {
        const int u = wv * 8 + i;              // 1KB unit (2 rows)
        const int r = u * 2 + (lane >> 5);     // chunk-local row 0..63
        const int j = (lane & 31) ^ (r & 7);   // logical 16B granule
        gl2lds16(W2c + r * 256 + j * 8, sW + u * 512);
      }
    }

    // epilogue: +bias, relu, pack straight into phase-2 A-frags (NO LDS)
    #pragma unroll
    for (int mt = 0; mt < 4; ++mt)
      #pragma unroll
      for (int nt = 0; nt < 4; ++nt) {
        float v0 = acc[mt][nt][0] + bias[mt][0]; v0 = v0 > 0.f ? v0 : 0.f;
        float v1 = acc[mt][nt][1] + bias[mt][1]; v1 = v1 > 0.f ? v1 : 0.f;
        float v2 = acc[mt][nt][2] + bias[mt][2]; v2 = v2 > 0.f ? v2 : 0.f;
        float v3 = acc[mt][nt][3] + bias[mt][3]; v3 = v3 > 0.f ? v3 : 0.f;
        s16x4 pk;
        pk[0] = (short)f2bf(v0); pk[1] = (short)f2bf(v1);
        pk[2] = (short)f2bf(v2); pk[3] = (short)f2bf(v3);
        aF[cc * 4 + mt][nt] = pk;
      }
  }

  __syncthreads();   // barrier #1: all waves done reading sU-as-st

  // ---- DMA chunk 1 -> sU (now free) ----
  #pragma unroll
  for (int i = 0; i < 8; ++i) {
    const int u = wv * 8 + i;
    const int r = u * 2 + (lane >> 5);
    const int j = (lane & 31) ^ (r & 7);
    gl2lds16(W2c + (64 + r) * 256 + j * 8, sU + u * 512);
  }
  __syncthreads();   // barrier #2: drains vmcnt(0) -> chunks 0,1 landed

  // ---- phase 2+3: d = relu(h1 @ W2 + b2) . W3, 4 chunks of 64 W2T rows ----
  float dacc[4][4];
  #pragma unroll
  for (int rt = 0; rt < 4; ++rt)
    #pragma unroll
    for (int r = 0; r < 4; ++r) dacc[rt][r] = 0.f;

  #pragma unroll
  for (int ch = 0; ch < 4; ++ch) {
    const unsigned short* buf = (ch & 1) ? sU : sW;

    // per-chunk scalars: issued BEFORE this iteration's DMA (vmcnt FIFO clean)
    float pb2v[4], pw3v[4];
    #pragma unroll
    for (int ct = 0; ct < 4; ++ct) {
      const int n = ch * 64 + ct * 16 + l15;
      pb2v[ct] = b2[c * HD + n];
      pw3v[ct] = W3[c * HD + n];
    }

    f32x4 acc[4][4];   // [rt(batch)][ct(h2-col)]
    #pragma unroll
    for (int rt = 0; rt < 4; ++rt)
      #pragma unroll
      for (int ct = 0; ct < 4; ++ct)
        acc[rt][ct] = (f32x4){0.f, 0.f, 0.f, 0.f};

    #pragma unroll
    for (int kk = 0; kk < 16; ++kk) {     // K=16 steps over hidden=256
      #pragma unroll
      for (int ct = 0; ct < 4; ++ct) {
        const int nl = ct * 16 + l15;     // chunk-local W2T row (= h2 col)
        const int p16 = (kk * 2 + (q >> 1)) ^ (nl & 7);
        s16x4 bW = *reinterpret_cast<const s16x4*>(
            buf + nl * 256 + p16 * 8 + (q & 1) * 4);
        #pragma unroll
        for (int rt = 0; rt < 4; ++rt)
          acc[rt][ct] = __builtin_amdgcn_mfma_f32_16x16x16bf16_1k(
              aF[kk][rt], bW, acc[rt][ct], 0, 0, 0);
      }
    }

    // fused epilogue: relu(h2 + b2) dot W3 per row
    #pragma unroll
    for (int ct = 0; ct < 4; ++ct) {
      const float bias = pb2v[ct];
      const float w3v  = pw3v[ct];
      #pragma unroll
      for (int rt = 0; rt < 4; ++rt)
        #pragma unroll
        for (int r = 0; r < 4; ++r) {
          float v = acc[rt][ct][r] + bias;
          v = v > 0.f ? v : 0.f;
          dacc[rt][r] += v * w3v;
        }
    }

    if (ch < 3) {
      __syncthreads();   // readers of buf done; drains next chunk's DMA
      if (ch < 2) {      // refill freed buffer with chunk ch+2
        unsigned short* nbuf = (ch & 1) ? sU : sW;
        #pragma unroll
        for (int i = 0; i < 8; ++i) {
          const int u = wv * 8 + i;
          const int r = u * 2 + (lane >> 5);
          const int j = (lane & 31) ^ (r & 7);
          gl2lds16(W2c + ((ch + 2) * 64 + r) * 256 + j * 8, nbuf + u * 512);
        }
      }
    }
  }

  // ---- reduce over the 16 col-lanes, write out ----
  #pragma unroll
  for (int rt = 0; rt < 4; ++rt)
    #pragma unroll
    for (int r = 0; r < 4; ++r) {
      float v = dacc[rt][r];
      v += __shfl_xor(v, 1);
      v += __shfl_xor(v, 2);
      v += __shfl_xor(v, 4);
      v += __shfl_xor(v, 8);
      dacc[rt][r] = v;
    }

  if (l15 == 0) {
    const int rbase = row0 + wv * 64 + q * 4;
    #pragma unroll
    for (int rt = 0; rt < 4; ++rt)
      #pragma unroll
      for (int r = 0; r < 4; ++r)
        out[(rbase + rt * 16 + r) * C + c] = dacc[rt][r] + bb3;
  }
}

extern "C" void kernel_launch(void* const* d_in, const int* in_sizes, int n_in,
                              void* d_out, int out_size, void* d_ws, size_t ws_size,
                              hipStream_t stream)
{
  const float* st = (const float*)d_in[0];
  const float* W1 = (const float*)d_in[1];
  const float* b1 = (const float*)d_in[2];
  const float* W2 = (const float*)d_in[3];
  const float* b2 = (const float*)d_in[4];
  const float* W3 = (const float*)d_in[5];
  const float* b3 = (const float*)d_in[6];
  float* out = (float*)d_out;

  unsigned short* W1T = (unsigned short*)d_ws;         // 131072 bf16
  unsigned short* W2T = W1T + C * HD * S;              // 524288 bf16

  prep_weights<<<dim3(640), dim3(256), 0, stream>>>(W1, W2, W1T, W2T);
  moe_fused<<<dim3(2048), dim3(256), 0, stream>>>(st, W1T, W2T, b1, b2, W3, b3, out);
}